// Round 1
// baseline (134.145 us; speedup 1.0000x reference)
//
#include <hip/hip_runtime.h>

#define B_   32
#define HW_  (512 * 512)
#define NSP  100
#define NSEG (B_ * NSP)
#define NTOT ((float)(B_ * (size_t)HW_))   // 8388608 = 2^23, exact in f32

// ---------------------------------------------------------------- init
__global__ void mvc_init(float* sums, float* cnts, float* out0) {
    int i = blockIdx.x * blockDim.x + threadIdx.x;
    if (i < NSEG) { sums[i] = 0.f; cnts[i] = 0.f; }
    if (i == 0) out0[0] = 0.f;
}

// ---------------------------------------------------------------- segment sums
// grid = (CHUNKS, B), 256 threads. LDS bins per block, one global atomic
// per (block, bin).
__global__ void mvc_segsum(const float* __restrict__ rgb,
                           const float* __restrict__ freq,
                           const int*   __restrict__ spx,
                           float* __restrict__ sums,
                           float* __restrict__ cnts) {
    __shared__ float ls[NSP];
    __shared__ float lc[NSP];
    const int b = blockIdx.y;
    for (int i = threadIdx.x; i < NSP; i += blockDim.x) { ls[i] = 0.f; lc[i] = 0.f; }
    __syncthreads();

    const float4* r4 = (const float4*)(rgb + (size_t)b * HW_);
    const float4* f4 = (const float4*)(freq + (size_t)b * HW_);
    const int4*   s4 = (const int4*)(spx + (size_t)b * HW_);
    const int n4 = HW_ / 4;
    for (int i = blockIdx.x * blockDim.x + threadIdx.x; i < n4;
         i += gridDim.x * blockDim.x) {
        float4 rv = r4[i];
        float4 fv = f4[i];
        int4   sv = s4[i];
        atomicAdd(&ls[sv.x], 0.5f * (rv.x + fv.x)); atomicAdd(&lc[sv.x], 1.f);
        atomicAdd(&ls[sv.y], 0.5f * (rv.y + fv.y)); atomicAdd(&lc[sv.y], 1.f);
        atomicAdd(&ls[sv.z], 0.5f * (rv.z + fv.z)); atomicAdd(&lc[sv.z], 1.f);
        atomicAdd(&ls[sv.w], 0.5f * (rv.w + fv.w)); atomicAdd(&lc[sv.w], 1.f);
    }
    __syncthreads();
    for (int i = threadIdx.x; i < NSP; i += blockDim.x) {
        if (lc[i] != 0.f) {
            atomicAdd(&sums[b * NSP + i], ls[i]);
            atomicAdd(&cnts[b * NSP + i], lc[i]);
        }
    }
}

// ---------------------------------------------------------------- means
__global__ void mvc_means(const float* __restrict__ sums,
                          const float* __restrict__ cnts,
                          float* __restrict__ means) {
    int i = blockIdx.x * blockDim.x + threadIdx.x;
    if (i < NSEG) means[i] = sums[i] / fmaxf(cnts[i], 1.f);
}

// ---------------------------------------------------------------- finalize
// grid = (CHUNKS, B), 256 threads. Writes tgt map, accumulates loss.
__global__ void mvc_finalize(const float* __restrict__ rgb,
                             const float* __restrict__ freq,
                             const int*   __restrict__ spx,
                             const int*   __restrict__ label,
                             const float* __restrict__ means,
                             float* __restrict__ out) {
    __shared__ float lm[NSP];
    const int b = blockIdx.y;
    const float pos = (label[b] != 0) ? 1.f : 0.f;
    for (int i = threadIdx.x; i < NSP; i += blockDim.x)
        lm[i] = pos * means[b * NSP + i];
    __syncthreads();

    const float4* r4 = (const float4*)(rgb + (size_t)b * HW_);
    const float4* f4 = (const float4*)(freq + (size_t)b * HW_);
    const int4*   s4 = (const int4*)(spx + (size_t)b * HW_);
    float4* t4 = (float4*)(out + 1 + (size_t)b * HW_);
    const int n4 = HW_ / 4;

    float acc = 0.f;
    for (int i = blockIdx.x * blockDim.x + threadIdx.x; i < n4;
         i += gridDim.x * blockDim.x) {
        float4 rv = r4[i];
        float4 fv = f4[i];
        int4   sv = s4[i];
        float t0 = lm[sv.x], t1 = lm[sv.y], t2 = lm[sv.z], t3 = lm[sv.w];
        t4[i] = make_float4(t0, t1, t2, t3);
        float d;
        d = rv.x - t0; acc += d * d;  d = fv.x - t0; acc += d * d;
        d = rv.y - t1; acc += d * d;  d = fv.y - t1; acc += d * d;
        d = rv.z - t2; acc += d * d;  d = fv.z - t2; acc += d * d;
        d = rv.w - t3; acc += d * d;  d = fv.w - t3; acc += d * d;
    }
    acc *= (1.f / NTOT);

    // wave64 reduce, then cross-wave via LDS, one atomic per block
    for (int off = 32; off > 0; off >>= 1) acc += __shfl_down(acc, off, 64);
    __shared__ float wsum[4];
    const int wid = threadIdx.x >> 6;
    if ((threadIdx.x & 63) == 0) wsum[wid] = acc;
    __syncthreads();
    if (threadIdx.x == 0)
        atomicAdd(out, wsum[0] + wsum[1] + wsum[2] + wsum[3]);
}

// ---------------------------------------------------------------- launch
extern "C" void kernel_launch(void* const* d_in, const int* in_sizes, int n_in,
                              void* d_out, int out_size, void* d_ws, size_t ws_size,
                              hipStream_t stream) {
    const float* rgb   = (const float*)d_in[0];
    const float* freq  = (const float*)d_in[1];
    const int*   label = (const int*)d_in[2];
    const int*   spx   = (const int*)d_in[3];
    float* out = (float*)d_out;

    float* sums  = (float*)d_ws;
    float* cnts  = sums + NSEG;
    float* means = cnts + NSEG;

    mvc_init<<<(NSEG + 255) / 256, 256, 0, stream>>>(sums, cnts, out);

    dim3 grid(64, B_);
    mvc_segsum<<<grid, 256, 0, stream>>>(rgb, freq, spx, sums, cnts);

    mvc_means<<<(NSEG + 255) / 256, 256, 0, stream>>>(sums, cnts, means);

    mvc_finalize<<<grid, 256, 0, stream>>>(rgb, freq, spx, label, means, out);
}

// Round 2
// 61.938 us; speedup vs baseline: 2.1658x; 2.1658x over previous
//
#include <hip/hip_runtime.h>

#define B_   32
#define HW_  (512 * 512)
#define NSP  100
#define NSEG (B_ * NSP)
#define NTOT ((float)(B_ * (size_t)HW_))   // 8388608 = 2^23, exact in f32

#define REP      8      // LDS bin-table replicas (indexed by lane&7)
#define RSTRIDE  101    // u64 stride between replicas (spreads bank bases)
#define FIXS     524288.f        // 2^19 fixed-point scale
#define FIXINV   (1.f / 524288.f)

// ---------------------------------------------------------------- init
__global__ void mvc_init(float* sums, float* cnts, float* out0) {
    int i = blockIdx.x * blockDim.x + threadIdx.x;
    if (i < NSEG) { sums[i] = 0.f; cnts[i] = 0.f; }
    if (i == 0) out0[0] = 0.f;
}

// ---------------------------------------------------------------- segment sums
// grid = (CHUNKS, B), 256 threads. One packed u64 LDS atomic per element:
// upper 32 bits = count, lower 32 bits = sum in 2^19 fixed point.
// Per-(block,bin) sum <= 4096 * 2^19 = 2^31 -> never carries into count.
__global__ void mvc_segsum(const float* __restrict__ rgb,
                           const float* __restrict__ freq,
                           const int*   __restrict__ spx,
                           float* __restrict__ sums,
                           float* __restrict__ cnts) {
    __shared__ unsigned long long bins[REP * RSTRIDE];
    const int b = blockIdx.y;
    for (int i = threadIdx.x; i < REP * RSTRIDE; i += blockDim.x) bins[i] = 0ull;
    __syncthreads();

    const int base = (threadIdx.x & (REP - 1)) * RSTRIDE;

    const float4* r4 = (const float4*)(rgb + (size_t)b * HW_);
    const float4* f4 = (const float4*)(freq + (size_t)b * HW_);
    const int4*   s4 = (const int4*)(spx + (size_t)b * HW_);
    const int n4 = HW_ / 4;
    for (int i = blockIdx.x * blockDim.x + threadIdx.x; i < n4;
         i += gridDim.x * blockDim.x) {
        float4 rv = r4[i];
        float4 fv = f4[i];
        int4   sv = s4[i];
        unsigned fx0 = (unsigned)(0.5f * (rv.x + fv.x) * FIXS + 0.5f);
        unsigned fx1 = (unsigned)(0.5f * (rv.y + fv.y) * FIXS + 0.5f);
        unsigned fx2 = (unsigned)(0.5f * (rv.z + fv.z) * FIXS + 0.5f);
        unsigned fx3 = (unsigned)(0.5f * (rv.w + fv.w) * FIXS + 0.5f);
        atomicAdd(&bins[base + sv.x], (1ull << 32) | (unsigned long long)fx0);
        atomicAdd(&bins[base + sv.y], (1ull << 32) | (unsigned long long)fx1);
        atomicAdd(&bins[base + sv.z], (1ull << 32) | (unsigned long long)fx2);
        atomicAdd(&bins[base + sv.w], (1ull << 32) | (unsigned long long)fx3);
    }
    __syncthreads();

    for (int i = threadIdx.x; i < NSP; i += blockDim.x) {
        unsigned long long c = 0, s = 0;
        #pragma unroll
        for (int r = 0; r < REP; ++r) {
            unsigned long long v = bins[r * RSTRIDE + i];
            c += v >> 32;
            s += v & 0xffffffffull;
        }
        if (c) {
            atomicAdd(&sums[b * NSP + i], (float)s * FIXINV);
            atomicAdd(&cnts[b * NSP + i], (float)c);
        }
    }
}

// ---------------------------------------------------------------- finalize
// grid = (CHUNKS, B), 256 threads. Computes per-bin means in LDS, writes
// tgt map, accumulates loss (one global atomic per block).
__global__ void mvc_finalize(const float* __restrict__ rgb,
                             const float* __restrict__ freq,
                             const int*   __restrict__ spx,
                             const int*   __restrict__ label,
                             const float* __restrict__ sums,
                             const float* __restrict__ cnts,
                             float* __restrict__ out) {
    __shared__ float lm[NSP];
    const int b = blockIdx.y;
    const float pos = (label[b] != 0) ? 1.f : 0.f;
    for (int i = threadIdx.x; i < NSP; i += blockDim.x) {
        float c = cnts[b * NSP + i];
        lm[i] = pos * sums[b * NSP + i] / fmaxf(c, 1.f);
    }
    __syncthreads();

    const float4* r4 = (const float4*)(rgb + (size_t)b * HW_);
    const float4* f4 = (const float4*)(freq + (size_t)b * HW_);
    const int4*   s4 = (const int4*)(spx + (size_t)b * HW_);
    float4* t4 = (float4*)(out + 1 + (size_t)b * HW_);
    const int n4 = HW_ / 4;

    float acc = 0.f;
    for (int i = blockIdx.x * blockDim.x + threadIdx.x; i < n4;
         i += gridDim.x * blockDim.x) {
        float4 rv = r4[i];
        float4 fv = f4[i];
        int4   sv = s4[i];
        float t0 = lm[sv.x], t1 = lm[sv.y], t2 = lm[sv.z], t3 = lm[sv.w];
        t4[i] = make_float4(t0, t1, t2, t3);
        float d;
        d = rv.x - t0; acc += d * d;  d = fv.x - t0; acc += d * d;
        d = rv.y - t1; acc += d * d;  d = fv.y - t1; acc += d * d;
        d = rv.z - t2; acc += d * d;  d = fv.z - t2; acc += d * d;
        d = rv.w - t3; acc += d * d;  d = fv.w - t3; acc += d * d;
    }
    acc *= (1.f / NTOT);

    for (int off = 32; off > 0; off >>= 1) acc += __shfl_down(acc, off, 64);
    __shared__ float wsum[4];
    const int wid = threadIdx.x >> 6;
    if ((threadIdx.x & 63) == 0) wsum[wid] = acc;
    __syncthreads();
    if (threadIdx.x == 0)
        atomicAdd(out, wsum[0] + wsum[1] + wsum[2] + wsum[3]);
}

// ---------------------------------------------------------------- launch
extern "C" void kernel_launch(void* const* d_in, const int* in_sizes, int n_in,
                              void* d_out, int out_size, void* d_ws, size_t ws_size,
                              hipStream_t stream) {
    const float* rgb   = (const float*)d_in[0];
    const float* freq  = (const float*)d_in[1];
    const int*   label = (const int*)d_in[2];
    const int*   spx   = (const int*)d_in[3];
    float* out = (float*)d_out;

    float* sums = (float*)d_ws;
    float* cnts = sums + NSEG;

    mvc_init<<<(NSEG + 255) / 256, 256, 0, stream>>>(sums, cnts, out);

    dim3 grid(64, B_);
    mvc_segsum<<<grid, 256, 0, stream>>>(rgb, freq, spx, sums, cnts);

    mvc_finalize<<<grid, 256, 0, stream>>>(rgb, freq, spx, label, sums, cnts, out);
}

// Round 3
// 59.039 us; speedup vs baseline: 2.2721x; 1.0491x over previous
//
#include <hip/hip_runtime.h>

#define B_   32
#define HW_  (512 * 512)
#define NSP  100
#define NSEG (B_ * NSP)
#define NTOT ((double)(B_ * (size_t)HW_))   // 8388608

#define REP      8      // LDS bin-table replicas (indexed by lane&7)
#define RSTRIDE  101    // u64 stride between replicas (spreads bank bases)
#define FIXS     524288.f        // 2^19 fixed-point scale
#define FIXINV   (1.f / 524288.f)

// ---------------------------------------------------------------- init
__global__ void mvc_init(float* sums, float* cnts, double* gsq) {
    int i = blockIdx.x * blockDim.x + threadIdx.x;
    if (i < NSEG) { sums[i] = 0.f; cnts[i] = 0.f; }
    if (i == 0) *gsq = 0.0;
}

// ---------------------------------------------------------------- segment sums
// grid = (CHUNKS, B), 256 threads. One packed u64 LDS atomic per element:
// upper 32 bits = count, lower 32 bits = sum of 0.5*(rgb+freq) in 2^19 fixed
// point (per-(block,bin) sum <= 4096*2^19 = 2^31 -> never carries into count).
// Also accumulates global sum(rgb^2 + freq^2) -> one f64 atomic per block.
__global__ void mvc_segsum(const float* __restrict__ rgb,
                           const float* __restrict__ freq,
                           const int*   __restrict__ spx,
                           float* __restrict__ sums,
                           float* __restrict__ cnts,
                           double* __restrict__ gsq) {
    __shared__ unsigned long long bins[REP * RSTRIDE];
    const int b = blockIdx.y;
    for (int i = threadIdx.x; i < REP * RSTRIDE; i += blockDim.x) bins[i] = 0ull;
    __syncthreads();

    const int base = (threadIdx.x & (REP - 1)) * RSTRIDE;

    const float4* r4 = (const float4*)(rgb + (size_t)b * HW_);
    const float4* f4 = (const float4*)(freq + (size_t)b * HW_);
    const int4*   s4 = (const int4*)(spx + (size_t)b * HW_);
    const int n4 = HW_ / 4;
    float sq = 0.f;
    for (int i = blockIdx.x * blockDim.x + threadIdx.x; i < n4;
         i += gridDim.x * blockDim.x) {
        float4 rv = r4[i];
        float4 fv = f4[i];
        int4   sv = s4[i];
        sq += rv.x * rv.x + fv.x * fv.x;
        sq += rv.y * rv.y + fv.y * fv.y;
        sq += rv.z * rv.z + fv.z * fv.z;
        sq += rv.w * rv.w + fv.w * fv.w;
        unsigned fx0 = (unsigned)(0.5f * (rv.x + fv.x) * FIXS + 0.5f);
        unsigned fx1 = (unsigned)(0.5f * (rv.y + fv.y) * FIXS + 0.5f);
        unsigned fx2 = (unsigned)(0.5f * (rv.z + fv.z) * FIXS + 0.5f);
        unsigned fx3 = (unsigned)(0.5f * (rv.w + fv.w) * FIXS + 0.5f);
        atomicAdd(&bins[base + sv.x], (1ull << 32) | (unsigned long long)fx0);
        atomicAdd(&bins[base + sv.y], (1ull << 32) | (unsigned long long)fx1);
        atomicAdd(&bins[base + sv.z], (1ull << 32) | (unsigned long long)fx2);
        atomicAdd(&bins[base + sv.w], (1ull << 32) | (unsigned long long)fx3);
    }
    __syncthreads();

    for (int i = threadIdx.x; i < NSP; i += blockDim.x) {
        unsigned long long c = 0, s = 0;
        #pragma unroll
        for (int r = 0; r < REP; ++r) {
            unsigned long long v = bins[r * RSTRIDE + i];
            c += v >> 32;
            s += v & 0xffffffffull;
        }
        if (c) {
            atomicAdd(&sums[b * NSP + i], (float)s * FIXINV);
            atomicAdd(&cnts[b * NSP + i], (float)c);
        }
    }

    // block-reduce sq -> one f64 atomic
    for (int off = 32; off > 0; off >>= 1) sq += __shfl_down(sq, off, 64);
    __shared__ float wsf[4];
    const int wid = threadIdx.x >> 6;
    if ((threadIdx.x & 63) == 0) wsf[wid] = sq;
    __syncthreads();
    if (threadIdx.x == 0)
        atomicAdd(gsq, (double)(wsf[0] + wsf[1] + wsf[2] + wsf[3]));
}

// ---------------------------------------------------------------- finalize
// grid = (CHUNKS, B), 256 threads. Reads ONLY spx; gathers per-bin target
// from LDS and writes the tgt map. Block (0,0) additionally computes the
// scalar loss from segment statistics (algebraic MSE expansion).
__global__ void mvc_finalize(const int*   __restrict__ spx,
                             const int*   __restrict__ label,
                             const float* __restrict__ sums,
                             const float* __restrict__ cnts,
                             const double* __restrict__ gsq,
                             float* __restrict__ out) {
    __shared__ float lm[NSP];
    const int b = blockIdx.y;
    const float pos = (label[b] != 0) ? 1.f : 0.f;
    for (int i = threadIdx.x; i < NSP; i += blockDim.x) {
        float c = cnts[b * NSP + i];
        lm[i] = pos * sums[b * NSP + i] / fmaxf(c, 1.f);
    }
    __syncthreads();

    const int4* s4 = (const int4*)(spx + (size_t)b * HW_);
    float4* t4 = (float4*)(out + 1 + (size_t)b * HW_);
    const int n4 = HW_ / 4;
    for (int i = blockIdx.x * blockDim.x + threadIdx.x; i < n4;
         i += gridDim.x * blockDim.x) {
        int4 sv = s4[i];
        t4[i] = make_float4(lm[sv.x], lm[sv.y], lm[sv.z], lm[sv.w]);
    }

    if (blockIdx.x == 0 && blockIdx.y == 0) {
        // loss*N = gsq - 4*sum_s t_s*S_s + 2*sum_s n_s*t_s^2
        double corr = 0.0;
        for (int i = threadIdx.x; i < NSEG; i += blockDim.x) {
            int bb = i / NSP;
            float n = cnts[i];
            float S = sums[i];
            float t = (label[bb] != 0) ? (S / fmaxf(n, 1.f)) : 0.f;
            corr += (double)(-4.f * t * S + 2.f * n * t * t);
        }
        for (int off = 32; off > 0; off >>= 1) corr += __shfl_down(corr, off, 64);
        __shared__ double wsd[4];
        const int wid = threadIdx.x >> 6;
        if ((threadIdx.x & 63) == 0) wsd[wid] = corr;
        __syncthreads();
        if (threadIdx.x == 0)
            out[0] = (float)((*gsq + wsd[0] + wsd[1] + wsd[2] + wsd[3]) / NTOT);
    }
}

// ---------------------------------------------------------------- launch
extern "C" void kernel_launch(void* const* d_in, const int* in_sizes, int n_in,
                              void* d_out, int out_size, void* d_ws, size_t ws_size,
                              hipStream_t stream) {
    const float* rgb   = (const float*)d_in[0];
    const float* freq  = (const float*)d_in[1];
    const int*   label = (const int*)d_in[2];
    const int*   spx   = (const int*)d_in[3];
    float* out = (float*)d_out;

    double* gsq  = (double*)d_ws;                 // 8B, aligned
    float*  sums = (float*)((char*)d_ws + 8);
    float*  cnts = sums + NSEG;

    mvc_init<<<(NSEG + 255) / 256, 256, 0, stream>>>(sums, cnts, gsq);

    dim3 grid(64, B_);
    mvc_segsum<<<grid, 256, 0, stream>>>(rgb, freq, spx, sums, cnts, gsq);

    mvc_finalize<<<grid, 256, 0, stream>>>(spx, label, sums, cnts, gsq, out);
}

// Round 4
// 41.034 us; speedup vs baseline: 3.2691x; 1.4388x over previous
//
#include <hip/hip_runtime.h>

#define B_     32
#define HW_    (512 * 512)
#define NSP    100
#define NSEG   (B_ * NSP)
#define NTOT   ((double)(B_ * (size_t)HW_))   // 8388608
#define CHUNKS 64                             // grid.x; 4096 elems/block/image

#define REP      16     // LDS bin-table replicas (indexed by tid&15)
#define RSTRIDE  101    // u32 stride between replicas (spreads bank bases)
// LDS u32 pack: count in bits [20:31], sum in [0:19] at 2^8 fixed point.
// Per-(block,bin): n <= 4095 (realistic ~75), sum <= n*256 < 2^20. No carry.
#define FIXS   256.f
#define FIXINV (1.f / 256.f)
// Global u64 pack: count << 44 | sum (global n <= 2^18, sum <= 2^26 << 2^44).
#define SUMMASK ((1ull << 44) - 1)

// ---------------------------------------------------------------- init
__global__ void mvc_init(unsigned long long* seg) {
    int i = blockIdx.x * blockDim.x + threadIdx.x;
    if (i < NSEG) seg[i] = 0ull;
}

// ---------------------------------------------------------------- segment sums
// grid = (CHUNKS, B), 256 threads. One u32 LDS atomic per element; one packed
// u64 global atomic per (block,bin); per-block sq partial STORED (no atomic).
__global__ void mvc_segsum(const float* __restrict__ rgb,
                           const float* __restrict__ freq,
                           const int*   __restrict__ spx,
                           unsigned long long* __restrict__ seg,
                           float* __restrict__ partials) {
    __shared__ unsigned bins[REP * RSTRIDE];
    const int b = blockIdx.y;
    for (int i = threadIdx.x; i < REP * RSTRIDE; i += blockDim.x) bins[i] = 0u;
    __syncthreads();

    const int base = (threadIdx.x & (REP - 1)) * RSTRIDE;

    const float4* r4 = (const float4*)(rgb + (size_t)b * HW_);
    const float4* f4 = (const float4*)(freq + (size_t)b * HW_);
    const int4*   s4 = (const int4*)(spx + (size_t)b * HW_);
    const int n4 = HW_ / 4;
    float sq = 0.f;
    for (int i = blockIdx.x * blockDim.x + threadIdx.x; i < n4;
         i += gridDim.x * blockDim.x) {
        float4 rv = r4[i];
        float4 fv = f4[i];
        int4   sv = s4[i];
        sq += rv.x * rv.x + fv.x * fv.x;
        sq += rv.y * rv.y + fv.y * fv.y;
        sq += rv.z * rv.z + fv.z * fv.z;
        sq += rv.w * rv.w + fv.w * fv.w;
        // 0.5*(r+f) * 2^8 = (r+f) * 128
        unsigned fx0 = (unsigned)((rv.x + fv.x) * 128.f + 0.5f);
        unsigned fx1 = (unsigned)((rv.y + fv.y) * 128.f + 0.5f);
        unsigned fx2 = (unsigned)((rv.z + fv.z) * 128.f + 0.5f);
        unsigned fx3 = (unsigned)((rv.w + fv.w) * 128.f + 0.5f);
        atomicAdd(&bins[base + sv.x], (1u << 20) | fx0);
        atomicAdd(&bins[base + sv.y], (1u << 20) | fx1);
        atomicAdd(&bins[base + sv.z], (1u << 20) | fx2);
        atomicAdd(&bins[base + sv.w], (1u << 20) | fx3);
    }
    __syncthreads();

    for (int i = threadIdx.x; i < NSP; i += blockDim.x) {
        unsigned long long c = 0, s = 0;
        #pragma unroll
        for (int r = 0; r < REP; ++r) {
            unsigned v = bins[r * RSTRIDE + i];
            c += v >> 20;
            s += v & 0xFFFFFu;
        }
        if (c) atomicAdd(&seg[b * NSP + i], (c << 44) | s);
    }

    // block-reduce sq -> plain store (no same-address contention)
    for (int off = 32; off > 0; off >>= 1) sq += __shfl_down(sq, off, 64);
    __shared__ float wsf[4];
    const int wid = threadIdx.x >> 6;
    if ((threadIdx.x & 63) == 0) wsf[wid] = sq;
    __syncthreads();
    if (threadIdx.x == 0)
        partials[blockIdx.y * CHUNKS + blockIdx.x] =
            wsf[0] + wsf[1] + wsf[2] + wsf[3];
}

// ---------------------------------------------------------------- finalize
// grid = (CHUNKS, B), 256 threads. Reads ONLY spx; gathers per-bin target
// from LDS, writes tgt map. Block (0,0) computes the scalar loss:
// loss*N = sum(rgb^2+freq^2) - 4*sum_s t_s*S_s + 2*sum_s n_s*t_s^2.
__global__ void mvc_finalize(const int*   __restrict__ spx,
                             const int*   __restrict__ label,
                             const unsigned long long* __restrict__ seg,
                             const float* __restrict__ partials,
                             float* __restrict__ out) {
    __shared__ float lm[NSP];
    const int b = blockIdx.y;
    const float pos = (label[b] != 0) ? 1.f : 0.f;
    for (int i = threadIdx.x; i < NSP; i += blockDim.x) {
        unsigned long long v = seg[b * NSP + i];
        float n = (float)(v >> 44);
        float S = (float)(v & SUMMASK) * FIXINV;
        lm[i] = pos * S / fmaxf(n, 1.f);
    }
    __syncthreads();

    const int4* s4 = (const int4*)(spx + (size_t)b * HW_);
    float4* t4 = (float4*)(out + 1 + (size_t)b * HW_);
    const int n4 = HW_ / 4;
    for (int i = blockIdx.x * blockDim.x + threadIdx.x; i < n4;
         i += gridDim.x * blockDim.x) {
        int4 sv = s4[i];
        t4[i] = make_float4(lm[sv.x], lm[sv.y], lm[sv.z], lm[sv.w]);
    }

    if (blockIdx.x == 0 && blockIdx.y == 0) {
        double corr = 0.0;
        for (int i = threadIdx.x; i < NSEG; i += blockDim.x) {
            unsigned long long v = seg[i];
            float n = (float)(v >> 44);
            float S = (float)(v & SUMMASK) * FIXINV;
            int bb = i / NSP;
            float t = (label[bb] != 0) ? (S / fmaxf(n, 1.f)) : 0.f;
            corr += -4.0 * (double)t * (double)S
                    + 2.0 * (double)n * (double)t * (double)t;
        }
        for (int i = threadIdx.x; i < CHUNKS * B_; i += blockDim.x)
            corr += (double)partials[i];
        for (int off = 32; off > 0; off >>= 1) corr += __shfl_down(corr, off, 64);
        __shared__ double wsd[4];
        const int wid = threadIdx.x >> 6;
        if ((threadIdx.x & 63) == 0) wsd[wid] = corr;
        __syncthreads();
        if (threadIdx.x == 0)
            out[0] = (float)((wsd[0] + wsd[1] + wsd[2] + wsd[3]) / NTOT);
    }
}

// ---------------------------------------------------------------- launch
extern "C" void kernel_launch(void* const* d_in, const int* in_sizes, int n_in,
                              void* d_out, int out_size, void* d_ws, size_t ws_size,
                              hipStream_t stream) {
    const float* rgb   = (const float*)d_in[0];
    const float* freq  = (const float*)d_in[1];
    const int*   label = (const int*)d_in[2];
    const int*   spx   = (const int*)d_in[3];
    float* out = (float*)d_out;

    unsigned long long* seg = (unsigned long long*)d_ws;       // NSEG u64
    float* partials = (float*)(seg + NSEG);                    // CHUNKS*B_ f32

    mvc_init<<<(NSEG + 255) / 256, 256, 0, stream>>>(seg);

    dim3 grid(CHUNKS, B_);
    mvc_segsum<<<grid, 256, 0, stream>>>(rgb, freq, spx, seg, partials);

    mvc_finalize<<<grid, 256, 0, stream>>>(spx, label, seg, partials, out);
}

// Round 6
// 37.845 us; speedup vs baseline: 3.5446x; 1.0843x over previous
//
#include <hip/hip_runtime.h>

#define B_      32
#define HW_     (512 * 512)
#define NSP     100
#define NTOT    ((double)(B_ * (size_t)HW_))   // 8388608

// --- K1 geometry ---
#define CHUNKS1 64
#define NBLK1   (CHUNKS1 * B_)        // 2048
// --- K2 geometry ---
#define CHUNKS2 32
#define F4PB2   (HW_ / 4 / CHUNKS2)   // 2048 float4 per block
#define ITERS2  (F4PB2 / 256)         // 8

#define REP      16     // LDS bin replicas (tid&15)
#define RSTRIDE  101    // u32 stride between replicas
// LDS u32 pack: count in [20:31], sum in [0:19] at 2^8 fixed point.
#define FIXINV  (1.f / 256.f)
// per-chunk u64 pack: count << 44 | sum.  Aggregated over 64 chunks:
// count <= 2^18, sum <= 2^26 << 2^44 -> no field carry.
#define SUMMASK ((1ull << 44) - 1)

// ---------------------------------------------------------------- K1
// grid = (CHUNKS1, B), 256 threads. LDS u32 bins; per-chunk partials and
// per-block sum-of-squares are STORED (no global atomics, no init kernel).
__global__ void mvc_segsum(const float* __restrict__ rgb,
                           const float* __restrict__ freq,
                           const int*   __restrict__ spx,
                           unsigned long long* __restrict__ partials, // [NBLK1][NSP]
                           float* __restrict__ sqp) {                 // [NBLK1]
    __shared__ unsigned bins[REP * RSTRIDE];
    const int tid = threadIdx.x;
    const int b = blockIdx.y;
    const int bid = b * CHUNKS1 + blockIdx.x;
    for (int i = tid; i < REP * RSTRIDE; i += 256) bins[i] = 0u;
    __syncthreads();

    const int base = (tid & (REP - 1)) * RSTRIDE;

    const float4* r4 = (const float4*)(rgb + (size_t)b * HW_);
    const float4* f4 = (const float4*)(freq + (size_t)b * HW_);
    const int4*   s4 = (const int4*)(spx + (size_t)b * HW_);
    const int n4 = HW_ / 4;
    float sq = 0.f;
    for (int i = blockIdx.x * 256 + tid; i < n4; i += CHUNKS1 * 256) {
        float4 rv = r4[i];
        float4 fv = f4[i];
        int4   sv = s4[i];
        sq += rv.x * rv.x + fv.x * fv.x;
        sq += rv.y * rv.y + fv.y * fv.y;
        sq += rv.z * rv.z + fv.z * fv.z;
        sq += rv.w * rv.w + fv.w * fv.w;
        unsigned fx0 = (unsigned)((rv.x + fv.x) * 128.f + 0.5f);
        unsigned fx1 = (unsigned)((rv.y + fv.y) * 128.f + 0.5f);
        unsigned fx2 = (unsigned)((rv.z + fv.z) * 128.f + 0.5f);
        unsigned fx3 = (unsigned)((rv.w + fv.w) * 128.f + 0.5f);
        atomicAdd(&bins[base + sv.x], (1u << 20) | fx0);
        atomicAdd(&bins[base + sv.y], (1u << 20) | fx1);
        atomicAdd(&bins[base + sv.z], (1u << 20) | fx2);
        atomicAdd(&bins[base + sv.w], (1u << 20) | fx3);
    }
    __syncthreads();

    for (int i = tid; i < NSP; i += 256) {
        unsigned long long cc = 0, ss = 0;
        #pragma unroll
        for (int r = 0; r < REP; ++r) {
            unsigned v = bins[r * RSTRIDE + i];
            cc += v >> 20;
            ss += v & 0xFFFFFu;
        }
        partials[(size_t)bid * NSP + i] = (cc << 44) | ss;   // unconditional
    }

    for (int off = 32; off > 0; off >>= 1) sq += __shfl_down(sq, off, 64);
    __shared__ float wsf[4];
    if ((tid & 63) == 0) wsf[tid >> 6] = sq;
    __syncthreads();
    if (tid == 0) sqp[bid] = wsf[0] + wsf[1] + wsf[2] + wsf[3];
}

// ---------------------------------------------------------------- K2
// grid = (CHUNKS2, B), 256 threads. Aggregates the image's 64 chunk-partials
// (L2/L3), builds the mean LUT, gathers spx (L3-resident), writes tgt map.
// c==0 blocks also emit the per-image loss correction term.
__global__ void mvc_finalize(const int*   __restrict__ spx,
                             const int*   __restrict__ label,
                             const unsigned long long* __restrict__ partials,
                             float* __restrict__ corrs,   // [B_]
                             float* __restrict__ out) {
    __shared__ unsigned long long ps[2 * NSP];
    __shared__ float lm[NSP];
    __shared__ float cr[NSP];
    const int tid = threadIdx.x;
    const int c = blockIdx.x, b = blockIdx.y;
    const float pos = (label[b] != 0) ? 1.f : 0.f;

    if (tid < 2 * NSP) {
        const int bin = tid % NSP, half = tid / NSP;
        const unsigned long long* pb =
            partials + ((size_t)b * CHUNKS1 + half * (CHUNKS1 / 2)) * NSP + bin;
        unsigned long long acc = 0;
        #pragma unroll 4
        for (int k = 0; k < CHUNKS1 / 2; ++k) acc += pb[(size_t)k * NSP];
        ps[tid] = acc;
    }
    __syncthreads();
    if (tid < NSP) {
        unsigned long long v = ps[tid] + ps[tid + NSP];
        float n = (float)(v >> 44);
        float S = (float)(v & SUMMASK) * FIXINV;
        float t = pos * S / fmaxf(n, 1.f);
        lm[tid] = t;
        cr[tid] = -4.f * t * S + 2.f * n * t * t;
    }
    __syncthreads();

    const int4* s4 = (const int4*)spx + (size_t)b * (HW_/4) + (size_t)c * F4PB2;
    float4* t4 = (float4*)(out + 1) + (size_t)b * (HW_/4) + (size_t)c * F4PB2;
    #pragma unroll
    for (int k = 0; k < ITERS2; ++k) {
        const int idx = k * 256 + tid;
        int4 sv = s4[idx];
        t4[idx] = make_float4(lm[sv.x], lm[sv.y], lm[sv.z], lm[sv.w]);
    }

    if (c == 0 && tid == 0) {
        float s = 0.f;
        for (int i = 0; i < NSP; ++i) s += cr[i];
        corrs[b] = s;
    }
}

// ---------------------------------------------------------------- K3
// 1 block. Deterministic fixed-order f64 reduction of sq-partials + corrs.
__global__ void mvc_loss(const float* __restrict__ sqp,
                         const float* __restrict__ corrs,
                         float* __restrict__ out) {
    const int tid = threadIdx.x;
    double s = 0.0;
    for (int i = tid; i < NBLK1; i += 256) s += (double)sqp[i];
    for (int off = 32; off > 0; off >>= 1) s += __shfl_down(s, off, 64);
    __shared__ double wsd[4];
    if ((tid & 63) == 0) wsd[tid >> 6] = s;
    __syncthreads();
    if (tid == 0) {
        double tot = wsd[0] + wsd[1] + wsd[2] + wsd[3];
        for (int i = 0; i < B_; ++i) tot += (double)corrs[i];
        out[0] = (float)(tot / NTOT);
    }
}

// ---------------------------------------------------------------- launch
extern "C" void kernel_launch(void* const* d_in, const int* in_sizes, int n_in,
                              void* d_out, int out_size, void* d_ws, size_t ws_size,
                              hipStream_t stream) {
    const float* rgb   = (const float*)d_in[0];
    const float* freq  = (const float*)d_in[1];
    const int*   label = (const int*)d_in[2];
    const int*   spx   = (const int*)d_in[3];
    float* out = (float*)d_out;

    unsigned long long* partials = (unsigned long long*)d_ws;     // 1.6 MB
    float* sqp   = (float*)(partials + (size_t)NBLK1 * NSP);      // 8 KB
    float* corrs = sqp + NBLK1;                                   // 128 B

    mvc_segsum<<<dim3(CHUNKS1, B_), 256, 0, stream>>>(rgb, freq, spx,
                                                      partials, sqp);
    mvc_finalize<<<dim3(CHUNKS2, B_), 256, 0, stream>>>(spx, label, partials,
                                                        corrs, out);
    mvc_loss<<<1, 256, 0, stream>>>(sqp, corrs, out);
}